// Round 11
// baseline (1154.206 us; speedup 1.0000x reference)
//
#include <hip/hip_runtime.h>
#include <stdint.h>

// Problem constants
#define Bb   128
#define Tt   256
#define Nn   4
#define Dd   64
#define Hh   256
#define G4H  1024          // 4*H
#define MR   64            // episode lanes (rows) per work item

// d_out layout: output (B,T,N,H) | h_n (B,N,L,H) | c_n (B,N,L,H)
#define OUT_HN 33554432    // 128*256*4*256
#define OUT_CN 33816576    // OUT_HN + 128*4*2*256

// workspace byte offsets
#define WS_CTRL 0          // 64 ints: [0]=stride mode, [1]=E, [2]=nchunks, [4..7]=work ctrs
#define WS_HIST 1024       // 257 ints
#define WS_SORT 8192       // 32768 u32 packed episodes (sorted desc by len)
#define WS_BIAS 139264     // N*2*1024 f32 packed bias
#define WS_WPK  262144     // packed bf16 weights: 4 agents * 1664 tiles * 1KB
#define TILES_PER_AGENT 1664   // 64 ntiles * (10 kb L0 + 16 kb L1)

typedef __attribute__((ext_vector_type(4))) float f32x4;
typedef __attribute__((ext_vector_type(8))) short bf16x8;

__device__ __forceinline__ unsigned short f2bf(float f){
  union { float f; unsigned u; } v; v.f = f;
  unsigned r = v.u + 0x7FFFu + ((v.u >> 16) & 1u);  // RNE
  return (unsigned short)(r >> 16);
}
__device__ __forceinline__ float bf2f(short s){
  union { unsigned u; float f; } v; v.u = ((unsigned)(unsigned short)s) << 16;
  return v.f;
}
// fast sigmoid / tanh via v_exp + v_rcp (absmax margin: 0.0039 vs 0.0231 threshold)
__device__ __forceinline__ float sigm(float x){
  return __builtin_amdgcn_rcpf(1.f + __expf(-x));
}
__device__ __forceinline__ float tanh_s(float x){
  return 1.f - 2.f * __builtin_amdgcn_rcpf(1.f + __expf(2.f * x));
}

// LDS-only barrier: drains DS ops (lgkmcnt) but NOT global stores (vmcnt).
// __syncthreads() emits s_waitcnt vmcnt(0) lgkmcnt(0) before s_barrier, which
// forces all waves to drain the output-store queue every step (the hidden
// per-step serializer). All cross-wave flows in the s-loop are LDS-only, so
// lgkmcnt(0) is the complete requirement (m201-verified pattern).
__device__ __forceinline__ void lds_barrier(){
  asm volatile("s_waitcnt lgkmcnt(0)" ::: "memory");
  __builtin_amdgcn_s_barrier();
  __builtin_amdgcn_sched_barrier(0);
}

// ---- LDS swizzle helpers (XOR bit4 with row&7 -> conflict-free b128 column reads) ----
__device__ __forceinline__ void st_h(unsigned short* hl, int row, int col, unsigned short v){
  int off = (row * (Hh*2) + col * 2) ^ ((row & 7) << 4);
  *(unsigned short*)((char*)hl + off) = v;
}
__device__ __forceinline__ bf16x8 ld_hfrag(const unsigned short* hl, int m, int kb, int l){
  int row = m*16 + (l & 15);
  int off = (row * (Hh*2) + kb*64 + ((l >> 4) << 4)) ^ ((row & 7) << 4);
  return *(const bf16x8*)((const char*)hl + off);
}
__device__ __forceinline__ bf16x8 ld_xfrag(const unsigned short* xl, int m, int kb, int l){
  int row = m*16 + (l & 15);
  int off = (row * (Dd*2) + kb*64 + ((l >> 4) << 4)) ^ ((row & 7) << 4);
  return *(const bf16x8*)((const char*)xl + off);
}

__device__ __forceinline__ bool get_flag(const unsigned char* p, int t, int stride){
  if (stride == 1) return p[t] != 0;
  return ((const int*)p)[t] != 0;   // covers int32 and f32 bit patterns
}

// ============== prep kernels (3 dispatches before k_main) ==============

__global__ void k_prep1(const unsigned char* ii, int* ctrl, int* hist){
  __shared__ int s_cnt;
  __shared__ int s_stride;
  int tid = threadIdx.x;          // 128 threads, one per b
  if (tid == 0) s_cnt = 0;
  __syncthreads();
  atomicAdd(&s_cnt, (ii[2*tid] != 0) + (ii[2*tid+1] != 0));
  __syncthreads();
  if (tid == 0){ s_stride = (s_cnt > 80) ? 1 : 4; ctrl[0] = s_stride; }
  __syncthreads();
  int stride = s_stride;
  const unsigned char* p = ii + (size_t)tid * Tt * stride;
  int start = 0;
  for (int t = 1; t < Tt; t++){
    if (get_flag(p, t, stride)){ atomicAdd(&hist[t - start], 1); start = t; }
  }
  atomicAdd(&hist[Tt - start], 1);
}

__global__ void k_prep2(const unsigned char* ii, int* ctrl, const int* hist,
                        unsigned int* sorted){
  __shared__ int offs_s[Tt + 1];
  int tid = threadIdx.x;          // 128 threads
  if (tid == 0){
    int run = 0;
    for (int len = Tt; len >= 1; len--){ offs_s[len] = run; run += hist[len]; }
    ctrl[1] = run;                     // E
    ctrl[2] = (run + MR - 1) / MR;     // nchunks
  }
  __syncthreads();
  int stride = ctrl[0];
  const unsigned char* p = ii + (size_t)tid * Tt * stride;
  int start = 0;
  for (int t = 1; t < Tt; t++){
    if (get_flag(p, t, stride)){
      int len = t - start;
      int pos = atomicAdd(&offs_s[len], 1);
      sorted[pos] = 0x80000000u | ((unsigned)tid << 16) | ((unsigned)start << 8) | (unsigned)(len - 1);
      start = t;
    }
  }
  int len = Tt - start;
  int pos = atomicAdd(&offs_s[len], 1);
  sorted[pos] = 0x80000000u | ((unsigned)tid << 16) | ((unsigned)start << 8) | (unsigned)(len - 1);
}

__global__ void k_packw(const float* __restrict__ Wih0, const float* __restrict__ Whh0,
                        const float* __restrict__ Wih1, const float* __restrict__ Whh1,
                        const float* __restrict__ bih0, const float* __restrict__ bhh0,
                        const float* __restrict__ bih1, const float* __restrict__ bhh1,
                        unsigned short* __restrict__ wpk, float* __restrict__ bpk){
  int bid = blockIdx.x;            // 0..6655
  int l = threadIdx.x;             // 0..63
  int n = bid / TILES_PER_AGENT;
  int r = bid % TILES_PER_AGENT;
  int layer, ntile, kb;
  if (r < 640){ layer = 0; ntile = r / 10; kb = r % 10; }
  else        { layer = 1; r -= 640; ntile = r / 16; kb = r % 16; }
  int col_sub = l >> 2;
  int k8      = (l & 3) * 8;
  int col  = ntile*16 + col_sub;
  int grow = (col & 3)*Hh + (col >> 2);
  const float* src;
  if (layer == 0){
    if (kb < 2) src = Wih0 + ((size_t)(n*G4H + grow))*Dd + kb*32 + k8;        // x part
    else        src = Whh0 + ((size_t)(n*G4H + grow))*Hh + (kb-2)*32 + k8;    // h0 part
  } else {
    if (kb < 8) src = Wih1 + ((size_t)(n*G4H + grow))*Hh + kb*32 + k8;        // h0_new part
    else        src = Whh1 + ((size_t)(n*G4H + grow))*Hh + (kb-8)*32 + k8;    // h1 part
  }
  int tl = (layer == 0) ? (ntile*10 + kb) : (640 + ntile*16 + kb);
  int lp = ((l & 3) << 4) | (l >> 2);
  unsigned short* dst = wpk + (((size_t)n*TILES_PER_AGENT + tl)*64 + lp)*8;
  #pragma unroll
  for (int j = 0; j < 8; j++) dst[j] = f2bf(src[j]);

  int id = bid*64 + l;
  if (id < Nn*2*G4H){
    int nb = id >> 11; int rb = id & 2047; int lyr = rb >> 10; int c = rb & 1023;
    int gr = (c & 3)*Hh + (c >> 2);
    float v = (lyr == 0) ? (bih0[nb*G4H + gr] + bhh0[nb*G4H + gr])
                         : (bih1[nb*G4H + gr] + bhh1[nb*G4H + gr]);
    bpk[id] = v;
  }
}

// ============== main kernel ==============
// 256 blocks x 512 threads, 1 block/CU ((512,1), R9-proven spill-free).
// Agent = blockIdx&3 (deterministic). Double-buffered LDS state (R10).
// R11: (a) ALL output stores are plain (NT removed) — NT stores ack from the
// HBM path and poisoned every vmcnt wait + barrier drain; (b) in-loop barriers
// are lds_barrier() = lgkmcnt(0)+s_barrier (no vmcnt drain) — all cross-wave
// flows in the s-loop are LDS-only (6 flows re-verified, each >=1 barrier
// separated); global stores are write-only and never need draining.
__launch_bounds__(512, 1)
__global__ void k_main(const float* __restrict__ x_in,
                       const unsigned short* __restrict__ wpk,
                       const float* __restrict__ bpk,
                       const unsigned int* __restrict__ sorted,
                       int* __restrict__ ctrl,
                       float* __restrict__ out)
{
  __shared__ unsigned short h0l[2][MR*Hh];  // 2x32KB, swizzled bf16
  __shared__ unsigned short h1l[2][MR*Hh];  // 2x32KB
  __shared__ unsigned short xl [2][MR*Dd];  // 2x8KB
  __shared__ unsigned short biasl[2*G4H];   // 4KB bf16 packed bias
  __shared__ unsigned int epl[MR];
  __shared__ int item_s;

  const int tid = threadIdx.x;
  const int w   = tid >> 6;
  const int l   = tid & 63;
  const int n   = blockIdx.x & 3;           // deterministic agent assignment
  const int E       = ctrl[1];
  const int nchunks = ctrl[2];

  const unsigned short* wbase = wpk + (size_t)n * TILES_PER_AGENT * 64 * 8;

  for (int i = tid; i < 2*G4H; i += 512) biasl[i] = f2bf(bpk[n*2*G4H + i]);

  const int nrow = l & 15;   // lane's episode row within M-tile
  const int nul  = l >> 4;   // lane's unit_local 0..3

  while (true){
    __syncthreads();
    if (tid == 0) item_s = atomicAdd(&ctrl[4 + n], 1);
    __syncthreads();
    int chunk = item_s;
    if (chunk >= nchunks) break;

    if (tid < MR){
      int idx = chunk*MR + tid;
      epl[tid] = (idx < E) ? sorted[idx] : 0u;
    }
    // zero cur(=0) state buffers
    for (int i = tid; i < MR*Hh/4; i += 512){
      ((ushort4*)h0l[0])[i] = make_ushort4(0,0,0,0);
      ((ushort4*)h1l[0])[i] = make_ushort4(0,0,0,0);
    }
    __syncthreads();   // epl visible (needed for x staging below)

    unsigned int ep0 = epl[0];
    int maxlen = (ep0 >> 31) ? (int)(ep0 & 255) + 1 : 0;  // sorted desc -> lane0 is max

    // stage x(s=0) into xl[0]
    #pragma unroll
    for (int r2 = 0; r2 < 2; r2++){
      int row = r2*32 + (tid >> 4);
      int d4  = (tid & 15) * 4;
      unsigned int pk = epl[row];
      int len = (pk >> 31) ? (int)(pk & 255) + 1 : 0;
      ushort4 u = make_ushort4(0,0,0,0);
      if (0 < len){
        int b = (pk >> 16) & 127;
        int t = (int)((pk >> 8) & 255);
        const float* xp = x_in + (((size_t)b*Tt + t)*Nn + n)*Dd + d4;
        f32x4 v = *(const f32x4*)xp;
        u.x = f2bf(v[0]); u.y = f2bf(v[1]); u.z = f2bf(v[2]); u.w = f2bf(v[3]);
      }
      int off = (row*(Dd*2) + d4*2) ^ ((row & 7) << 4);
      *(ushort4*)((char*)xl[0] + off) = u;
    }
    __syncthreads();   // x0 + zeroed state visible

    float c0r[8][4], c1r[8][4];
    #pragma unroll
    for (int i = 0; i < 8; i++)
      #pragma unroll
      for (int m = 0; m < 4; m++){ c0r[i][m]=0.f; c1r[i][m]=0.f; }

    int cur = 0;
    #pragma unroll 1
    for (int s = 0; s < maxlen; s++){
      const int nxt = cur ^ 1;
      const unsigned short* h0c = h0l[cur];
      const unsigned short* h1c = h1l[cur];
      const unsigned short* xc  = xl[cur];
      unsigned short* h0n = h0l[nxt];
      unsigned short* h1n = h1l[nxt];

      // ---- P1a: output-write(s-1) from h1l[cur] (overlaps L0 GEMM) ----
      if (s > 0){
        #pragma unroll
        for (int r2 = 0; r2 < 2; r2++){
          int row = r2*32 + (tid >> 4);
          unsigned int pk = epl[row];
          int len = (pk >> 31) ? (int)(pk & 255) + 1 : 0;
          if (s-1 < len){
            int b = (pk >> 16) & 127;
            int t = (int)((pk >> 8) & 255) + (s-1);
            int l16 = tid & 15;
            int swz = (row & 7) << 4;
            float* op = out + (((size_t)b*Tt + t)*Nn + n)*Hh;
            #pragma unroll
            for (int k = 0; k < 4; k++){
              int off = (row*(Hh*2) + k*128 + l16*8) ^ swz;
              ushort4 u = *(const ushort4*)((const char*)h1c + off);
              f32x4 v = { bf2f((short)u.x), bf2f((short)u.y), bf2f((short)u.z), bf2f((short)u.w) };
              *(f32x4*)(op + k*64 + l16*4) = v;
            }
          }
        }
      }

      // ---- P1b: LAYER 0 GEMM (reads xc, h0c) ----
      {
        f32x4 acc[8][4];
        #pragma unroll
        for (int i = 0; i < 8; i++){
          ushort4 bu = *(const ushort4*)&biasl[(w*8 + i)*16 + nul*4];
          f32x4 bv = { bf2f((short)bu.x), bf2f((short)bu.y),
                       bf2f((short)bu.z), bf2f((short)bu.w) };
          #pragma unroll
          for (int m = 0; m < 4; m++) acc[i][m] = bv;
        }
        #pragma unroll 1
        for (int kb = 0; kb < 10; kb++){
          bf16x8 a0, a1, a2, a3;
          if (kb < 2){
            a0 = ld_xfrag(xc, 0, kb, l); a1 = ld_xfrag(xc, 1, kb, l);
            a2 = ld_xfrag(xc, 2, kb, l); a3 = ld_xfrag(xc, 3, kb, l);
          } else {
            a0 = ld_hfrag(h0c, 0, kb-2, l); a1 = ld_hfrag(h0c, 1, kb-2, l);
            a2 = ld_hfrag(h0c, 2, kb-2, l); a3 = ld_hfrag(h0c, 3, kb-2, l);
          }
          #pragma unroll
          for (int i = 0; i < 8; i++){
            const bf16x8 bf = *(const bf16x8*)(wbase + (((size_t)((w*8+i)*10 + kb))*64 + l)*8);
            acc[i][0] = __builtin_amdgcn_mfma_f32_16x16x32_bf16(bf, a0, acc[i][0], 0, 0, 0);
            acc[i][1] = __builtin_amdgcn_mfma_f32_16x16x32_bf16(bf, a1, acc[i][1], 0, 0, 0);
            acc[i][2] = __builtin_amdgcn_mfma_f32_16x16x32_bf16(bf, a2, acc[i][2], 0, 0, 0);
            acc[i][3] = __builtin_amdgcn_mfma_f32_16x16x32_bf16(bf, a3, acc[i][3], 0, 0, 0);
          }
        }

        // L0 nonlin: writes h0l[nxt] — no conflict with readers of h0l[cur]
        #pragma unroll
        for (int i = 0; i < 8; i++){
          #pragma unroll
          for (int m = 0; m < 4; m++){
            f32x4 g = acc[i][m];
            float cn = sigm(g[1])*c0r[i][m] + sigm(g[0])*tanh_s(g[2]);
            float hn = sigm(g[3])*tanh_s(cn);
            c0r[i][m] = cn;
            int row  = m*16 + nrow;
            int unit = (w*8 + i)*4 + nul;
            st_h(h0n, row, unit, f2bf(hn));
            unsigned int pk = epl[row];
            if (pk >> 31){
              int len = (int)(pk & 255) + 1;
              int start = (pk >> 8) & 255;
              if (s == len - 1 && start + len == Tt){
                int b = (pk >> 16) & 127;
                size_t base = ((size_t)(b*Nn + n)*2 + 0)*Hh + unit;
                out[OUT_HN + base] = hn;
                out[OUT_CN + base] = cn;
              }
            }
          }
        }
      }
      lds_barrier();   // barrier alpha: h0_new visible (LDS-only; no store drain)

      // ---- P2a: stage x(s+1) into xl[nxt] (overlaps L1 GEMM) ----
      if (s + 1 < maxlen){
        #pragma unroll
        for (int r2 = 0; r2 < 2; r2++){
          int row = r2*32 + (tid >> 4);
          int d4  = (tid & 15) * 4;
          unsigned int pk = epl[row];
          int len = (pk >> 31) ? (int)(pk & 255) + 1 : 0;
          ushort4 u = make_ushort4(0,0,0,0);
          if (s + 1 < len){
            int b = (pk >> 16) & 127;
            int t = (int)((pk >> 8) & 255) + s + 1;
            const float* xp = x_in + (((size_t)b*Tt + t)*Nn + n)*Dd + d4;
            f32x4 v = *(const f32x4*)xp;
            u.x = f2bf(v[0]); u.y = f2bf(v[1]); u.z = f2bf(v[2]); u.w = f2bf(v[3]);
          }
          int off = (row*(Dd*2) + d4*2) ^ ((row & 7) << 4);
          *(ushort4*)((char*)xl[nxt] + off) = u;
        }
      }

      // ---- P2b: LAYER 1 GEMM (reads h0l[nxt], h1l[cur]) ----
      {
        f32x4 acc[8][4];
        #pragma unroll
        for (int i = 0; i < 8; i++){
          ushort4 bu = *(const ushort4*)&biasl[G4H + (w*8 + i)*16 + nul*4];
          f32x4 bv = { bf2f((short)bu.x), bf2f((short)bu.y),
                       bf2f((short)bu.z), bf2f((short)bu.w) };
          #pragma unroll
          for (int m = 0; m < 4; m++) acc[i][m] = bv;
        }
        #pragma unroll 1
        for (int kb = 0; kb < 16; kb++){
          bf16x8 a0, a1, a2, a3;
          if (kb < 8){
            a0 = ld_hfrag(h0n, 0, kb, l); a1 = ld_hfrag(h0n, 1, kb, l);
            a2 = ld_hfrag(h0n, 2, kb, l); a3 = ld_hfrag(h0n, 3, kb, l);
          } else {
            a0 = ld_hfrag(h1c, 0, kb-8, l); a1 = ld_hfrag(h1c, 1, kb-8, l);
            a2 = ld_hfrag(h1c, 2, kb-8, l); a3 = ld_hfrag(h1c, 3, kb-8, l);
          }
          #pragma unroll
          for (int i = 0; i < 8; i++){
            const bf16x8 bf = *(const bf16x8*)(wbase + (((size_t)(640 + (w*8+i)*16 + kb))*64 + l)*8);
            acc[i][0] = __builtin_amdgcn_mfma_f32_16x16x32_bf16(bf, a0, acc[i][0], 0, 0, 0);
            acc[i][1] = __builtin_amdgcn_mfma_f32_16x16x32_bf16(bf, a1, acc[i][1], 0, 0, 0);
            acc[i][2] = __builtin_amdgcn_mfma_f32_16x16x32_bf16(bf, a2, acc[i][2], 0, 0, 0);
            acc[i][3] = __builtin_amdgcn_mfma_f32_16x16x32_bf16(bf, a3, acc[i][3], 0, 0, 0);
          }
        }

        // L1 nonlin: writes h1l[nxt]
        #pragma unroll
        for (int i = 0; i < 8; i++){
          #pragma unroll
          for (int m = 0; m < 4; m++){
            f32x4 g = acc[i][m];
            float cn = sigm(g[1])*c1r[i][m] + sigm(g[0])*tanh_s(g[2]);
            float hn = sigm(g[3])*tanh_s(cn);
            c1r[i][m] = cn;
            int row  = m*16 + nrow;
            int unit = (w*8 + i)*4 + nul;
            st_h(h1n, row, unit, f2bf(hn));
            unsigned int pk = epl[row];
            if (pk >> 31){
              int len = (int)(pk & 255) + 1;
              int start = (pk >> 8) & 255;
              if (s == len - 1 && start + len == Tt){
                int b = (pk >> 16) & 127;
                size_t base = ((size_t)(b*Nn + n)*2 + 1)*Hh + unit;
                out[OUT_HN + base] = hn;
                out[OUT_CN + base] = cn;
              }
            }
          }
        }
      }
      lds_barrier();   // barrier beta: h1_new + x(s+1) visible (LDS-only)
      cur = nxt;
    } // s loop

    // ---- epilogue: output-write for the last step from h1l[cur] ----
    if (maxlen > 0){
      int s = maxlen - 1;
      const unsigned short* h1c = h1l[cur];
      #pragma unroll
      for (int r2 = 0; r2 < 2; r2++){
        int row = r2*32 + (tid >> 4);
        unsigned int pk = epl[row];
        int len = (pk >> 31) ? (int)(pk & 255) + 1 : 0;
        if (s < len){
          int b = (pk >> 16) & 127;
          int t = (int)((pk >> 8) & 255) + s;
          int l16 = tid & 15;
          int swz = (row & 7) << 4;
          float* op = out + (((size_t)b*Tt + t)*Nn + n)*Hh;
          #pragma unroll
          for (int k = 0; k < 4; k++){
            int off = (row*(Hh*2) + k*128 + l16*8) ^ swz;
            ushort4 u = *(const ushort4*)((const char*)h1c + off);
            f32x4 v = { bf2f((short)u.x), bf2f((short)u.y), bf2f((short)u.z), bf2f((short)u.w) };
            *(f32x4*)(op + k*64 + l16*4) = v;
          }
        }
      }
    }
  } // work loop
}

// ============== launch ==============
extern "C" void kernel_launch(void* const* d_in, const int* in_sizes, int n_in,
                              void* d_out, int out_size, void* d_ws, size_t ws_size,
                              hipStream_t stream)
{
  const float* x    = (const float*)d_in[0];
  const unsigned char* ii = (const unsigned char*)d_in[1];
  const float* Wih0 = (const float*)d_in[2];
  const float* Whh0 = (const float*)d_in[3];
  const float* bih0 = (const float*)d_in[4];
  const float* bhh0 = (const float*)d_in[5];
  const float* Wih1 = (const float*)d_in[6];
  const float* Whh1 = (const float*)d_in[7];
  const float* bih1 = (const float*)d_in[8];
  const float* bhh1 = (const float*)d_in[9];
  float* out = (float*)d_out;
  char* ws = (char*)d_ws;

  int* ctrl = (int*)(ws + WS_CTRL);
  int* hist = (int*)(ws + WS_HIST);
  unsigned int* sorted = (unsigned int*)(ws + WS_SORT);
  float* bpk = (float*)(ws + WS_BIAS);
  unsigned short* wpkp = (unsigned short*)(ws + WS_WPK);

  hipMemsetAsync(d_ws, 0, 8192, stream);
  k_prep1 <<<1, 128, 0, stream>>>(ii, ctrl, hist);
  k_prep2 <<<1, 128, 0, stream>>>(ii, ctrl, hist, sorted);
  k_packw <<<Nn*TILES_PER_AGENT, 64, 0, stream>>>(Wih0, Whh0, Wih1, Whh1,
                                                  bih0, bhh0, bih1, bhh1, wpkp, bpk);
  k_main  <<<256, 512, 0, stream>>>(x, wpkp, bpk, sorted, ctrl, out);
}

// Round 12
// 939.590 us; speedup vs baseline: 1.2284x; 1.2284x over previous
//
#include <hip/hip_runtime.h>
#include <stdint.h>

// Problem constants
#define Bb   128
#define Tt   256
#define Nn   4
#define Dd   64
#define Hh   256
#define G4H  1024          // 4*H
#define MR   64            // episode lanes (rows) per work item

// d_out layout: output (B,T,N,H) | h_n (B,N,L,H) | c_n (B,N,L,H)
#define OUT_HN 33554432    // 128*256*4*256
#define OUT_CN 33816576    // OUT_HN + 128*4*2*256

// workspace byte offsets
#define WS_CTRL 0          // 64 ints: [0]=stride mode, [1]=E, [2]=nchunks, [4..7]=work ctrs
#define WS_HIST 1024       // 257 ints
#define WS_SORT 8192       // 32768 u32 packed episodes (sorted desc by len)
#define WS_BIAS 139264     // N*2*1024 f32 packed bias
#define WS_WPK  262144     // packed bf16 weights: 4 agents * 1664 tiles * 1KB
#define TILES_PER_AGENT 1664   // 64 ntiles * (10 kb L0 + 16 kb L1)

typedef __attribute__((ext_vector_type(4))) float f32x4;
typedef __attribute__((ext_vector_type(8))) short bf16x8;

__device__ __forceinline__ unsigned short f2bf(float f){
  union { float f; unsigned u; } v; v.f = f;
  unsigned r = v.u + 0x7FFFu + ((v.u >> 16) & 1u);  // RNE
  return (unsigned short)(r >> 16);
}
__device__ __forceinline__ float bf2f(short s){
  union { unsigned u; float f; } v; v.u = ((unsigned)(unsigned short)s) << 16;
  return v.f;
}
__device__ __forceinline__ float sigm(float x){
  return __builtin_amdgcn_rcpf(1.f + __expf(-x));
}
__device__ __forceinline__ float tanh_s(float x){
  return 1.f - 2.f * __builtin_amdgcn_rcpf(1.f + __expf(2.f * x));
}

// LDS-only barrier: drains DS ops but NOT vmcnt -> in-flight global_load_lds
// weight prefetches survive across barriers (the whole point of R12).
__device__ __forceinline__ void lds_barrier(){
  asm volatile("s_waitcnt lgkmcnt(0)" ::: "memory");
  __builtin_amdgcn_s_barrier();
  __builtin_amdgcn_sched_barrier(0);
}
#define WAITVM4() do { asm volatile("s_waitcnt vmcnt(4)" ::: "memory"); \
                       __builtin_amdgcn_sched_barrier(0); } while(0)
#define WAITLGKM0() do { asm volatile("s_waitcnt lgkmcnt(0)" ::: "memory"); \
                         __builtin_amdgcn_sched_barrier(0); } while(0)

// ---- LDS swizzle helpers (XOR bit4 with row&7 -> conflict-free b128 column reads) ----
__device__ __forceinline__ void st_h(unsigned short* hl, int row, int col, unsigned short v){
  int off = (row * (Hh*2) + col * 2) ^ ((row & 7) << 4);
  *(unsigned short*)((char*)hl + off) = v;
}
__device__ __forceinline__ bf16x8 ld_hfrag(const unsigned short* hl, int m, int kb, int l){
  int row = m*16 + (l & 15);
  int off = (row * (Hh*2) + kb*64 + ((l >> 4) << 4)) ^ ((row & 7) << 4);
  return *(const bf16x8*)((const char*)hl + off);
}
__device__ __forceinline__ bf16x8 ld_xfrag(const unsigned short* xl, int m, int kb, int l){
  int row = m*16 + (l & 15);
  int off = (row * (Dd*2) + kb*64 + ((l >> 4) << 4)) ^ ((row & 7) << 4);
  return *(const bf16x8*)((const char*)xl + off);
}

__device__ __forceinline__ bool get_flag(const unsigned char* p, int t, int stride){
  if (stride == 1) return p[t] != 0;
  return ((const int*)p)[t] != 0;
}

// ============== prep kernels ==============

__global__ void k_prep1(const unsigned char* ii, int* ctrl, int* hist){
  __shared__ int s_cnt;
  __shared__ int s_stride;
  int tid = threadIdx.x;          // 128 threads, one per b
  if (tid == 0) s_cnt = 0;
  __syncthreads();
  atomicAdd(&s_cnt, (ii[2*tid] != 0) + (ii[2*tid+1] != 0));
  __syncthreads();
  if (tid == 0){ s_stride = (s_cnt > 80) ? 1 : 4; ctrl[0] = s_stride; }
  __syncthreads();
  int stride = s_stride;
  const unsigned char* p = ii + (size_t)tid * Tt * stride;
  int start = 0;
  for (int t = 1; t < Tt; t++){
    if (get_flag(p, t, stride)){ atomicAdd(&hist[t - start], 1); start = t; }
  }
  atomicAdd(&hist[Tt - start], 1);
}

__global__ void k_prep2(const unsigned char* ii, int* ctrl, const int* hist,
                        unsigned int* sorted){
  __shared__ int offs_s[Tt + 1];
  int tid = threadIdx.x;          // 128 threads
  if (tid == 0){
    int run = 0;
    for (int len = Tt; len >= 1; len--){ offs_s[len] = run; run += hist[len]; }
    ctrl[1] = run;                     // E
    ctrl[2] = (run + MR - 1) / MR;     // nchunks
  }
  __syncthreads();
  int stride = ctrl[0];
  const unsigned char* p = ii + (size_t)tid * Tt * stride;
  int start = 0;
  for (int t = 1; t < Tt; t++){
    if (get_flag(p, t, stride)){
      int len = t - start;
      int pos = atomicAdd(&offs_s[len], 1);
      sorted[pos] = 0x80000000u | ((unsigned)tid << 16) | ((unsigned)start << 8) | (unsigned)(len - 1);
      start = t;
    }
  }
  int len = Tt - start;
  int pos = atomicAdd(&offs_s[len], 1);
  sorted[pos] = 0x80000000u | ((unsigned)tid << 16) | ((unsigned)start << 8) | (unsigned)(len - 1);
}

__global__ void k_packw(const float* __restrict__ Wih0, const float* __restrict__ Whh0,
                        const float* __restrict__ Wih1, const float* __restrict__ Whh1,
                        const float* __restrict__ bih0, const float* __restrict__ bhh0,
                        const float* __restrict__ bih1, const float* __restrict__ bhh1,
                        unsigned short* __restrict__ wpk, float* __restrict__ bpk){
  int bid = blockIdx.x;            // 0..6655
  int l = threadIdx.x;             // 0..63
  int n = bid / TILES_PER_AGENT;
  int r = bid % TILES_PER_AGENT;
  int layer, ntile, kb;
  if (r < 640){ layer = 0; ntile = r / 10; kb = r % 10; }
  else        { layer = 1; r -= 640; ntile = r / 16; kb = r % 16; }
  int col_sub = l >> 2;
  int k8      = (l & 3) * 8;
  int col  = ntile*16 + col_sub;
  int grow = (col & 3)*Hh + (col >> 2);
  const float* src;
  if (layer == 0){
    if (kb < 2) src = Wih0 + ((size_t)(n*G4H + grow))*Dd + kb*32 + k8;
    else        src = Whh0 + ((size_t)(n*G4H + grow))*Hh + (kb-2)*32 + k8;
  } else {
    if (kb < 8) src = Wih1 + ((size_t)(n*G4H + grow))*Hh + kb*32 + k8;
    else        src = Whh1 + ((size_t)(n*G4H + grow))*Hh + (kb-8)*32 + k8;
  }
  int tl = (layer == 0) ? (ntile*10 + kb) : (640 + ntile*16 + kb);
  int lp = ((l & 3) << 4) | (l >> 2);
  unsigned short* dst = wpk + (((size_t)n*TILES_PER_AGENT + tl)*64 + lp)*8;
  #pragma unroll
  for (int j = 0; j < 8; j++) dst[j] = f2bf(src[j]);

  int id = bid*64 + l;
  if (id < Nn*2*G4H){
    int nb = id >> 11; int rb = id & 2047; int lyr = rb >> 10; int c = rb & 1023;
    int gr = (c & 3)*Hh + (c >> 2);
    float v = (lyr == 0) ? (bih0[nb*G4H + gr] + bhh0[nb*G4H + gr])
                         : (bih1[nb*G4H + gr] + bhh1[nb*G4H + gr]);
    bpk[id] = v;
  }
}

// ============== main kernel ==============
// 256 blocks x 512 threads, 1 block/CU ((512,1): 256-reg cap, R9-proven).
// R12 WEIGHT PIPELINE: R9-R11 were bound by SERIALIZED weight loads (~94us/step
// = 26kb x ~8 loads x ~900cyc; zero MLP because the register file is at the
// 256-reg cap -> compiler keeps ~1 load in flight). Weights now stream via
// global_load_lds (NO VGPR cost) into a per-wave 2x4KB LDS rotation, with a
// continuous unit chain across layers AND steps (prefetch crosses barriers:
// lds_barrier drains lgkm only). Uniform s_waitcnt vmcnt(4) keeps 2 units
// (8 loads) in flight at all times.
__launch_bounds__(512, 1)
__global__ void k_main(const float* __restrict__ x_in,
                       const unsigned short* __restrict__ wpk,
                       const float* __restrict__ bpk,
                       const unsigned int* __restrict__ sorted,
                       int* __restrict__ ctrl,
                       float* __restrict__ out)
{
  __shared__ unsigned short h0l[MR*Hh];     // 32KB, swizzled bf16 (single buffer)
  __shared__ unsigned short h1l[MR*Hh];     // 32KB
  __shared__ unsigned short xl [MR*Dd];     // 8KB
  __shared__ unsigned short biasl[2*G4H];   // 4KB bf16 packed bias
  __shared__ unsigned short wbuf[8][4096];  // 64KB: per-wave 2 units x 4 tiles x 512
  __shared__ unsigned int epl[MR];
  __shared__ int item_s;

  const int tid = threadIdx.x;
  const int w   = tid >> 6;
  const int l   = tid & 63;
  const int n   = blockIdx.x & 3;
  const int E       = ctrl[1];
  const int nchunks = ctrl[2];

  const unsigned short* wbase = wpk + (size_t)n * TILES_PER_AGENT * 64 * 8;
  unsigned short* wwave = wbuf[w];

  for (int i = tid; i < 2*G4H; i += 512) biasl[i] = f2bf(bpk[n*2*G4H + i]);

  const int nrow = l & 15;
  const int nul  = l >> 4;

  // Issue one weight unit: 4 tiles (4KB/wave) into parity half `ih`.
  // layer 0: tile(i,kb) = (w*8+i)*10+kb ; layer 1: 640+(w*8+i)*16+kb.
  auto issue_unit = [&](int layer, int kb, int ih){
    unsigned short* dst = wwave + ih*2048;
    int base   = (layer == 0) ? ((w*8 + ih*4)*10 + kb) : (640 + (w*8 + ih*4)*16 + kb);
    int stride = (layer == 0) ? 10 : 16;
    #pragma unroll
    for (int i = 0; i < 4; i++){
      const unsigned short* src = wbase + ((size_t)(base + i*stride)*64 + l)*8;
      __builtin_amdgcn_global_load_lds(
          (const __attribute__((address_space(1))) void*)src,
          (__attribute__((address_space(3))) void*)(dst + i*512), 16, 0, 0);
    }
  };

  while (true){
    __syncthreads();                         // full drain (chunk boundary)
    if (tid == 0) item_s = atomicAdd(&ctrl[4 + n], 1);
    __syncthreads();
    int chunk = item_s;
    if (chunk >= nchunks) break;

    if (tid < MR){
      int idx = chunk*MR + tid;
      epl[tid] = (idx < E) ? sorted[idx] : 0u;
    }
    for (int i = tid; i < MR*Hh/4; i += 512){
      ((ushort4*)h0l)[i] = make_ushort4(0,0,0,0);
      ((ushort4*)h1l)[i] = make_ushort4(0,0,0,0);
    }
    __syncthreads();

    unsigned int ep0 = epl[0];
    int maxlen = (ep0 >> 31) ? (int)(ep0 & 255) + 1 : 0;

    float c0r[8][4], c1r[8][4];
    #pragma unroll
    for (int i = 0; i < 8; i++)
      #pragma unroll
      for (int m = 0; m < 4; m++){ c0r[i][m]=0.f; c1r[i][m]=0.f; }

    // prime the weight pipeline: L0 kb=0, both halves
    issue_unit(0, 0, 0);
    issue_unit(0, 0, 1);

    #pragma unroll 1
    for (int s = 0; s < maxlen; s++){
      // ---- stage x_t (fp32 -> bf16, swizzled; zeros for finished lanes) ----
      #pragma unroll
      for (int r2 = 0; r2 < 2; r2++){
        int row = r2*32 + (tid >> 4);
        int d4  = (tid & 15) * 4;
        unsigned int pk = epl[row];
        int len = (pk >> 31) ? (int)(pk & 255) + 1 : 0;
        ushort4 u = make_ushort4(0,0,0,0);
        if (s < len){
          int b = (pk >> 16) & 127;
          int t = (int)((pk >> 8) & 255) + s;
          const float* xp = x_in + (((size_t)b*Tt + t)*Nn + n)*Dd + d4;
          f32x4 v = *(const f32x4*)xp;
          u.x = f2bf(v[0]); u.y = f2bf(v[1]); u.z = f2bf(v[2]); u.w = f2bf(v[3]);
        }
        int off = (row*(Dd*2) + d4*2) ^ ((row & 7) << 4);
        *(ushort4*)((char*)xl + off) = u;
      }
      lds_barrier();                                   // bar 1: xl ready

      // ================= LAYER 0 GEMM =================
      {
        f32x4 acc[8][4];
        #pragma unroll
        for (int i = 0; i < 8; i++){
          ushort4 bu = *(const ushort4*)&biasl[(w*8 + i)*16 + nul*4];
          f32x4 bv = { bf2f((short)bu.x), bf2f((short)bu.y),
                       bf2f((short)bu.z), bf2f((short)bu.w) };
          #pragma unroll
          for (int m = 0; m < 4; m++) acc[i][m] = bv;
        }
        #pragma unroll 1
        for (int kb = 0; kb < 10; kb++){
          bf16x8 a0, a1, a2, a3;
          if (kb < 2){
            a0 = ld_xfrag(xl, 0, kb, l); a1 = ld_xfrag(xl, 1, kb, l);
            a2 = ld_xfrag(xl, 2, kb, l); a3 = ld_xfrag(xl, 3, kb, l);
          } else {
            a0 = ld_hfrag(h0l, 0, kb-2, l); a1 = ld_hfrag(h0l, 1, kb-2, l);
            a2 = ld_hfrag(h0l, 2, kb-2, l); a3 = ld_hfrag(h0l, 3, kb-2, l);
          }
          #pragma unroll
          for (int ih = 0; ih < 2; ih++){
            WAITVM4();                       // unit (kb,ih) resident; (kb,ih^1)/(kb+1,ih) in flight
            const unsigned short* rb = wwave + ih*2048;
            bf16x8 w0 = *(const bf16x8*)(rb + (size_t)l*8);
            bf16x8 w1 = *(const bf16x8*)(rb +  512 + (size_t)l*8);
            bf16x8 w2 = *(const bf16x8*)(rb + 1024 + (size_t)l*8);
            bf16x8 w3 = *(const bf16x8*)(rb + 1536 + (size_t)l*8);
            WAITLGKM0();                     // w0..w3 in regs; safe to overwrite buffer
            if (kb + 1 < 10) issue_unit(0, kb + 1, ih);
            else             issue_unit(1, 0,      ih);   // L1 prologue crosses barriers
            int i0 = ih*4;
            acc[i0+0][0] = __builtin_amdgcn_mfma_f32_16x16x32_bf16(w0, a0, acc[i0+0][0], 0, 0, 0);
            acc[i0+0][1] = __builtin_amdgcn_mfma_f32_16x16x32_bf16(w0, a1, acc[i0+0][1], 0, 0, 0);
            acc[i0+0][2] = __builtin_amdgcn_mfma_f32_16x16x32_bf16(w0, a2, acc[i0+0][2], 0, 0, 0);
            acc[i0+0][3] = __builtin_amdgcn_mfma_f32_16x16x32_bf16(w0, a3, acc[i0+0][3], 0, 0, 0);
            acc[i0+1][0] = __builtin_amdgcn_mfma_f32_16x16x32_bf16(w1, a0, acc[i0+1][0], 0, 0, 0);
            acc[i0+1][1] = __builtin_amdgcn_mfma_f32_16x16x32_bf16(w1, a1, acc[i0+1][1], 0, 0, 0);
            acc[i0+1][2] = __builtin_amdgcn_mfma_f32_16x16x32_bf16(w1, a2, acc[i0+1][2], 0, 0, 0);
            acc[i0+1][3] = __builtin_amdgcn_mfma_f32_16x16x32_bf16(w1, a3, acc[i0+1][3], 0, 0, 0);
            acc[i0+2][0] = __builtin_amdgcn_mfma_f32_16x16x32_bf16(w2, a0, acc[i0+2][0], 0, 0, 0);
            acc[i0+2][1] = __builtin_amdgcn_mfma_f32_16x16x32_bf16(w2, a1, acc[i0+2][1], 0, 0, 0);
            acc[i0+2][2] = __builtin_amdgcn_mfma_f32_16x16x32_bf16(w2, a2, acc[i0+2][2], 0, 0, 0);
            acc[i0+2][3] = __builtin_amdgcn_mfma_f32_16x16x32_bf16(w2, a3, acc[i0+2][3], 0, 0, 0);
            acc[i0+3][0] = __builtin_amdgcn_mfma_f32_16x16x32_bf16(w3, a0, acc[i0+3][0], 0, 0, 0);
            acc[i0+3][1] = __builtin_amdgcn_mfma_f32_16x16x32_bf16(w3, a1, acc[i0+3][1], 0, 0, 0);
            acc[i0+3][2] = __builtin_amdgcn_mfma_f32_16x16x32_bf16(w3, a2, acc[i0+3][2], 0, 0, 0);
            acc[i0+3][3] = __builtin_amdgcn_mfma_f32_16x16x32_bf16(w3, a3, acc[i0+3][3], 0, 0, 0);
          }
        }
        lds_barrier();   // bar 2: all waves done reading h0l(old)/xl

        // L0 nonlin: gates in acc regs; writes h0l (new)
        #pragma unroll
        for (int i = 0; i < 8; i++){
          #pragma unroll
          for (int m = 0; m < 4; m++){
            f32x4 g = acc[i][m];
            float cn = sigm(g[1])*c0r[i][m] + sigm(g[0])*tanh_s(g[2]);
            float hn = sigm(g[3])*tanh_s(cn);
            c0r[i][m] = cn;
            int row  = m*16 + nrow;
            int unit = (w*8 + i)*4 + nul;
            st_h(h0l, row, unit, f2bf(hn));
            unsigned int pk = epl[row];
            if (pk >> 31){
              int len = (int)(pk & 255) + 1;
              int start = (pk >> 8) & 255;
              if (s == len - 1 && start + len == Tt){
                int b = (pk >> 16) & 127;
                size_t base = ((size_t)(b*Nn + n)*2 + 0)*Hh + unit;
                out[OUT_HN + base] = hn;
                out[OUT_CN + base] = cn;
              }
            }
          }
        }
      }
      lds_barrier();   // bar 3: h0_new visible

      // ================= LAYER 1 GEMM =================
      {
        f32x4 acc[8][4];
        #pragma unroll
        for (int i = 0; i < 8; i++){
          ushort4 bu = *(const ushort4*)&biasl[G4H + (w*8 + i)*16 + nul*4];
          f32x4 bv = { bf2f((short)bu.x), bf2f((short)bu.y),
                       bf2f((short)bu.z), bf2f((short)bu.w) };
          #pragma unroll
          for (int m = 0; m < 4; m++) acc[i][m] = bv;
        }
        #pragma unroll 1
        for (int kb = 0; kb < 16; kb++){
          bf16x8 a0, a1, a2, a3;
          if (kb < 8){
            a0 = ld_hfrag(h0l, 0, kb, l); a1 = ld_hfrag(h0l, 1, kb, l);
            a2 = ld_hfrag(h0l, 2, kb, l); a3 = ld_hfrag(h0l, 3, kb, l);
          } else {
            a0 = ld_hfrag(h1l, 0, kb-8, l); a1 = ld_hfrag(h1l, 1, kb-8, l);
            a2 = ld_hfrag(h1l, 2, kb-8, l); a3 = ld_hfrag(h1l, 3, kb-8, l);
          }
          #pragma unroll
          for (int ih = 0; ih < 2; ih++){
            WAITVM4();
            const unsigned short* rb = wwave + ih*2048;
            bf16x8 w0 = *(const bf16x8*)(rb + (size_t)l*8);
            bf16x8 w1 = *(const bf16x8*)(rb +  512 + (size_t)l*8);
            bf16x8 w2 = *(const bf16x8*)(rb + 1024 + (size_t)l*8);
            bf16x8 w3 = *(const bf16x8*)(rb + 1536 + (size_t)l*8);
            WAITLGKM0();
            if (kb + 1 < 16)            issue_unit(1, kb + 1, ih);
            else if (s + 1 < maxlen)    issue_unit(0, 0, ih);     // next step's L0
            int i0 = ih*4;
            acc[i0+0][0] = __builtin_amdgcn_mfma_f32_16x16x32_bf16(w0, a0, acc[i0+0][0], 0, 0, 0);
            acc[i0+0][1] = __builtin_amdgcn_mfma_f32_16x16x32_bf16(w0, a1, acc[i0+0][1], 0, 0, 0);
            acc[i0+0][2] = __builtin_amdgcn_mfma_f32_16x16x32_bf16(w0, a2, acc[i0+0][2], 0, 0, 0);
            acc[i0+0][3] = __builtin_amdgcn_mfma_f32_16x16x32_bf16(w0, a3, acc[i0+0][3], 0, 0, 0);
            acc[i0+1][0] = __builtin_amdgcn_mfma_f32_16x16x32_bf16(w1, a0, acc[i0+1][0], 0, 0, 0);
            acc[i0+1][1] = __builtin_amdgcn_mfma_f32_16x16x32_bf16(w1, a1, acc[i0+1][1], 0, 0, 0);
            acc[i0+1][2] = __builtin_amdgcn_mfma_f32_16x16x32_bf16(w1, a2, acc[i0+1][2], 0, 0, 0);
            acc[i0+1][3] = __builtin_amdgcn_mfma_f32_16x16x32_bf16(w1, a3, acc[i0+1][3], 0, 0, 0);
            acc[i0+2][0] = __builtin_amdgcn_mfma_f32_16x16x32_bf16(w2, a0, acc[i0+2][0], 0, 0, 0);
            acc[i0+2][1] = __builtin_amdgcn_mfma_f32_16x16x32_bf16(w2, a1, acc[i0+2][1], 0, 0, 0);
            acc[i0+2][2] = __builtin_amdgcn_mfma_f32_16x16x32_bf16(w2, a2, acc[i0+2][2], 0, 0, 0);
            acc[i0+2][3] = __builtin_amdgcn_mfma_f32_16x16x32_bf16(w2, a3, acc[i0+2][3], 0, 0, 0);
            acc[i0+3][0] = __builtin_amdgcn_mfma_f32_16x16x32_bf16(w3, a0, acc[i0+3][0], 0, 0, 0);
            acc[i0+3][1] = __builtin_amdgcn_mfma_f32_16x16x32_bf16(w3, a1, acc[i0+3][1], 0, 0, 0);
            acc[i0+3][2] = __builtin_amdgcn_mfma_f32_16x16x32_bf16(w3, a2, acc[i0+3][2], 0, 0, 0);
            acc[i0+3][3] = __builtin_amdgcn_mfma_f32_16x16x32_bf16(w3, a3, acc[i0+3][3], 0, 0, 0);
          }
        }
        lds_barrier();   // bar 4: all waves done reading h0_new/h1l(old)

        // L1 nonlin: writes h1l (new)
        #pragma unroll
        for (int i = 0; i < 8; i++){
          #pragma unroll
          for (int m = 0; m < 4; m++){
            f32x4 g = acc[i][m];
            float cn = sigm(g[1])*c1r[i][m] + sigm(g[0])*tanh_s(g[2]);
            float hn = sigm(g[3])*tanh_s(cn);
            c1r[i][m] = cn;
            int row  = m*16 + nrow;
            int unit = (w*8 + i)*4 + nul;
            st_h(h1l, row, unit, f2bf(hn));
            unsigned int pk = epl[row];
            if (pk >> 31){
              int len = (int)(pk & 255) + 1;
              int start = (pk >> 8) & 255;
              if (s == len - 1 && start + len == Tt){
                int b = (pk >> 16) & 127;
                size_t base = ((size_t)(b*Nn + n)*2 + 1)*Hh + unit;
                out[OUT_HN + base] = hn;
                out[OUT_CN + base] = cn;
              }
            }
          }
        }
      }
      lds_barrier();   // bar 5: h1_new visible for output read

      // ---- output write: output[b, t, n, :] = h1_new (256B segments) ----
      #pragma unroll
      for (int r2 = 0; r2 < 2; r2++){
        int row = r2*32 + (tid >> 4);
        unsigned int pk = epl[row];
        int len = (pk >> 31) ? (int)(pk & 255) + 1 : 0;
        if (s < len){
          int b = (pk >> 16) & 127;
          int t = (int)((pk >> 8) & 255) + s;
          int l16 = tid & 15;
          int swz = (row & 7) << 4;
          float* op = out + (((size_t)b*Tt + t)*Nn + n)*Hh;
          #pragma unroll
          for (int k = 0; k < 4; k++){
            int off = (row*(Hh*2) + k*128 + l16*8) ^ swz;
            ushort4 u = *(const ushort4*)((const char*)h1l + off);
            f32x4 v = { bf2f((short)u.x), bf2f((short)u.y), bf2f((short)u.z), bf2f((short)u.w) };
            *(f32x4*)(op + k*64 + l16*4) = v;
          }
        }
      }
      // no trailing barrier: next h1l writers are >=3 barriers away
    } // s loop
  } // work loop
}

// ============== launch ==============
extern "C" void kernel_launch(void* const* d_in, const int* in_sizes, int n_in,
                              void* d_out, int out_size, void* d_ws, size_t ws_size,
                              hipStream_t stream)
{
  const float* x    = (const float*)d_in[0];
  const unsigned char* ii = (const unsigned char*)d_in[1];
  const float* Wih0 = (const float*)d_in[2];
  const float* Whh0 = (const float*)d_in[3];
  const float* bih0 = (const float*)d_in[4];
  const float* bhh0 = (const float*)d_in[5];
  const float* Wih1 = (const float*)d_in[6];
  const float* Whh1 = (const float*)d_in[7];
  const float* bih1 = (const float*)d_in[8];
  const float* bhh1 = (const float*)d_in[9];
  float* out = (float*)d_out;
  char* ws = (char*)d_ws;

  int* ctrl = (int*)(ws + WS_CTRL);
  int* hist = (int*)(ws + WS_HIST);
  unsigned int* sorted = (unsigned int*)(ws + WS_SORT);
  float* bpk = (float*)(ws + WS_BIAS);
  unsigned short* wpkp = (unsigned short*)(ws + WS_WPK);

  hipMemsetAsync(d_ws, 0, 8192, stream);
  k_prep1 <<<1, 128, 0, stream>>>(ii, ctrl, hist);
  k_prep2 <<<1, 128, 0, stream>>>(ii, ctrl, hist, sorted);
  k_packw <<<Nn*TILES_PER_AGENT, 64, 0, stream>>>(Wih0, Whh0, Wih1, Whh1,
                                                  bih0, bhh0, bih1, bhh1, wpkp, bpk);
  k_main  <<<256, 512, 0, stream>>>(x, wpkp, bpk, sorted, ctrl, out);
}

// Round 13
// 856.958 us; speedup vs baseline: 1.3469x; 1.0964x over previous
//
#include <hip/hip_runtime.h>
#include <stdint.h>

// Problem constants
#define Bb   128
#define Tt   256
#define Nn   4
#define Dd   64
#define Hh   256
#define G4H  1024          // 4*H
#define MR   32            // episode lanes (rows) per work item (R13: halved for 2 blocks/CU)

// d_out layout: output (B,T,N,H) | h_n (B,N,L,H) | c_n (B,N,L,H)
#define OUT_HN 33554432    // 128*256*4*256
#define OUT_CN 33816576    // OUT_HN + 128*4*2*256

// workspace byte offsets
#define WS_CTRL 0          // 64 ints: [0]=stride mode, [1]=E, [2]=nchunks, [4..7]=work ctrs
#define WS_SORT 8192       // 32768 u32 packed episodes (sorted desc by len)
#define WS_BIAS 139264     // N*2*1024 f32 packed bias
#define WS_WPK  262144     // packed bf16 weights: 4 agents * 1664 tiles * 1KB
#define TILES_PER_AGENT 1664   // 64 ntiles * (10 kb L0 + 16 kb L1)

typedef __attribute__((ext_vector_type(4))) float f32x4;
typedef __attribute__((ext_vector_type(8))) short bf16x8;

__device__ __forceinline__ unsigned short f2bf(float f){
  union { float f; unsigned u; } v; v.f = f;
  unsigned r = v.u + 0x7FFFu + ((v.u >> 16) & 1u);  // RNE
  return (unsigned short)(r >> 16);
}
__device__ __forceinline__ float bf2f(short s){
  union { unsigned u; float f; } v; v.u = ((unsigned)(unsigned short)s) << 16;
  return v.f;
}
__device__ __forceinline__ float sigm(float x){
  return __builtin_amdgcn_rcpf(1.f + __expf(-x));
}
__device__ __forceinline__ float tanh_s(float x){
  return 1.f - 2.f * __builtin_amdgcn_rcpf(1.f + __expf(2.f * x));
}

// LDS-only barrier: drains DS ops but NOT vmcnt -> in-flight global_load_lds
// weight prefetches survive across barriers.
__device__ __forceinline__ void lds_barrier(){
  asm volatile("s_waitcnt lgkmcnt(0)" ::: "memory");
  __builtin_amdgcn_s_barrier();
  __builtin_amdgcn_sched_barrier(0);
}
#define WAITVM4() do { asm volatile("s_waitcnt vmcnt(4)" ::: "memory"); \
                       __builtin_amdgcn_sched_barrier(0); } while(0)
#define WAITLGKM0() do { asm volatile("s_waitcnt lgkmcnt(0)" ::: "memory"); \
                         __builtin_amdgcn_sched_barrier(0); } while(0)

// ---- LDS swizzle helpers (XOR bit4 with row&7 -> conflict-free b128 column reads) ----
__device__ __forceinline__ void st_h(unsigned short* hl, int row, int col, unsigned short v){
  int off = (row * (Hh*2) + col * 2) ^ ((row & 7) << 4);
  *(unsigned short*)((char*)hl + off) = v;
}
__device__ __forceinline__ bf16x8 ld_hfrag(const unsigned short* hl, int m, int kb, int l){
  int row = m*16 + (l & 15);
  int off = (row * (Hh*2) + kb*64 + ((l >> 4) << 4)) ^ ((row & 7) << 4);
  return *(const bf16x8*)((const char*)hl + off);
}
__device__ __forceinline__ bf16x8 ld_xfrag(const unsigned short* xl, int m, int kb, int l){
  int row = m*16 + (l & 15);
  int off = (row * (Dd*2) + kb*64 + ((l >> 4) << 4)) ^ ((row & 7) << 4);
  return *(const bf16x8*)((const char*)xl + off);
}

__device__ __forceinline__ bool get_flag(const unsigned char* p, int t, int stride){
  if (stride == 1) return p[t] != 0;
  return ((const int*)p)[t] != 0;
}

// ============== prep kernels (2 dispatches before k_main) ==============

// Fused: detect stride + histogram + scan + scatter (one 128-thread block).
__global__ void k_prep(const unsigned char* ii, int* ctrl, unsigned int* sorted){
  __shared__ int s_cnt;
  __shared__ int hist_s[Tt + 1];
  __shared__ int offs_s[Tt + 1];
  int tid = threadIdx.x;          // 128 threads, one per b
  if (tid == 0) s_cnt = 0;
  for (int i = tid; i <= Tt; i += 128) hist_s[i] = 0;
  __syncthreads();
  atomicAdd(&s_cnt, (ii[2*tid] != 0) + (ii[2*tid+1] != 0));
  __syncthreads();
  int stride = (s_cnt > 80) ? 1 : 4;
  if (tid == 0) ctrl[0] = stride;
  const unsigned char* p = ii + (size_t)tid * Tt * stride;
  int start = 0;
  for (int t = 1; t < Tt; t++){
    if (get_flag(p, t, stride)){ atomicAdd(&hist_s[t - start], 1); start = t; }
  }
  atomicAdd(&hist_s[Tt - start], 1);
  __syncthreads();
  if (tid == 0){
    int run = 0;
    for (int len = Tt; len >= 1; len--){ offs_s[len] = run; run += hist_s[len]; }
    ctrl[1] = run;                     // E
    ctrl[2] = (run + MR - 1) / MR;     // nchunks
  }
  __syncthreads();
  start = 0;
  for (int t = 1; t < Tt; t++){
    if (get_flag(p, t, stride)){
      int len = t - start;
      int pos = atomicAdd(&offs_s[len], 1);
      sorted[pos] = 0x80000000u | ((unsigned)tid << 16) | ((unsigned)start << 8) | (unsigned)(len - 1);
      start = t;
    }
  }
  int len = Tt - start;
  int pos = atomicAdd(&offs_s[len], 1);
  sorted[pos] = 0x80000000u | ((unsigned)tid << 16) | ((unsigned)start << 8) | (unsigned)(len - 1);
}

__global__ void k_packw(const float* __restrict__ Wih0, const float* __restrict__ Whh0,
                        const float* __restrict__ Wih1, const float* __restrict__ Whh1,
                        const float* __restrict__ bih0, const float* __restrict__ bhh0,
                        const float* __restrict__ bih1, const float* __restrict__ bhh1,
                        unsigned short* __restrict__ wpk, float* __restrict__ bpk){
  int bid = blockIdx.x;            // 0..6655
  int l = threadIdx.x;             // 0..63
  int n = bid / TILES_PER_AGENT;
  int r = bid % TILES_PER_AGENT;
  int layer, ntile, kb;
  if (r < 640){ layer = 0; ntile = r / 10; kb = r % 10; }
  else        { layer = 1; r -= 640; ntile = r / 16; kb = r % 16; }
  int col_sub = l >> 2;
  int k8      = (l & 3) * 8;
  int col  = ntile*16 + col_sub;
  int grow = (col & 3)*Hh + (col >> 2);
  const float* src;
  if (layer == 0){
    if (kb < 2) src = Wih0 + ((size_t)(n*G4H + grow))*Dd + kb*32 + k8;
    else        src = Whh0 + ((size_t)(n*G4H + grow))*Hh + (kb-2)*32 + k8;
  } else {
    if (kb < 8) src = Wih1 + ((size_t)(n*G4H + grow))*Hh + kb*32 + k8;
    else        src = Whh1 + ((size_t)(n*G4H + grow))*Hh + (kb-8)*32 + k8;
  }
  int tl = (layer == 0) ? (ntile*10 + kb) : (640 + ntile*16 + kb);
  int lp = ((l & 3) << 4) | (l >> 2);
  unsigned short* dst = wpk + (((size_t)n*TILES_PER_AGENT + tl)*64 + lp)*8;
  #pragma unroll
  for (int j = 0; j < 8; j++) dst[j] = f2bf(src[j]);

  int id = bid*64 + l;
  if (id < Nn*2*G4H){
    int nb = id >> 11; int rb = id & 2047; int lyr = rb >> 10; int c = rb & 1023;
    int gr = (c & 3)*Hh + (c >> 2);
    float v = (lyr == 0) ? (bih0[nb*G4H + gr] + bhh0[nb*G4H + gr])
                         : (bih1[nb*G4H + gr] + bhh1[nb*G4H + gr]);
    bpk[id] = v;
  }
}

// ============== main kernel ==============
// R13: 512 blocks x 256 threads (4 waves), 2 blocks/CU. R12 showed Occupancy
// 15.3% (CUs empty 40% of dispatch) and loaded per-step ~3x the serial-chain
// model: a single 8-wave barrier-locked block cannot hide its own waits.
// Two INDEPENDENT blocks per CU overlap each other's barrier/lgkm/vmcnt
// stalls. MR=32 halves per-block state: acc[16][2](128) + c(64) + frags ~240
// regs <= the 256-reg cap at 2 waves/SIMD (__launch_bounds__(256,2) -> 2
// blocks/CU; R9 precedent: ~240 fits, no spill). LDS 72KB/block -> 2 resident.
// R12 weight pipeline kept: per-wave 2x4KB LDS rotation, unit=4 tiles,
// 4 sub-stages/kb, vmcnt(4), chain crosses barriers (lds_barrier = lgkm only).
__launch_bounds__(256, 2)
__global__ void k_main(const float* __restrict__ x_in,
                       const unsigned short* __restrict__ wpk,
                       const float* __restrict__ bpk,
                       const unsigned int* __restrict__ sorted,
                       int* __restrict__ ctrl,
                       float* __restrict__ out)
{
  __shared__ unsigned short h0l[MR*Hh];     // 16KB, swizzled bf16
  __shared__ unsigned short h1l[MR*Hh];     // 16KB
  __shared__ unsigned short xl [MR*Dd];     // 4KB
  __shared__ unsigned short biasl[2*G4H];   // 4KB bf16 packed bias
  __shared__ unsigned short wbuf[4][4096];  // 32KB: per-wave 2 halves x 4 tiles x 512
  __shared__ unsigned int epl[MR];
  __shared__ int item_s;

  const int tid = threadIdx.x;
  const int w   = tid >> 6;                 // wave 0..3
  const int l   = tid & 63;
  const int n   = blockIdx.x & 3;
  const int E       = ctrl[1];
  const int nchunks = ctrl[2];

  const unsigned short* wbase = wpk + (size_t)n * TILES_PER_AGENT * 64 * 8;
  unsigned short* wwave = wbuf[w];

  for (int i = tid; i < 2*G4H; i += 256) biasl[i] = f2bf(bpk[n*2*G4H + i]);

  const int nrow = l & 15;
  const int nul  = l >> 4;

  // Issue one weight unit: 4 tiles (4KB/wave) into parity half `half`.
  // Wave w owns tiles w*16 + (u*4+j), j<4. L0 tile id=(t)*10+kb, L1=640+(t)*16+kb.
  auto issue_unit = [&](int layer, int kb, int u, int half){
    unsigned short* dst = wwave + half*2048;
    int t0     = w*16 + u*4;
    int base   = (layer == 0) ? ((t0)*10 + kb) : (640 + (t0)*16 + kb);
    int stride = (layer == 0) ? 10 : 16;
    #pragma unroll
    for (int j = 0; j < 4; j++){
      const unsigned short* src = wbase + ((size_t)(base + j*stride)*64 + l)*8;
      __builtin_amdgcn_global_load_lds(
          (const __attribute__((address_space(1))) void*)src,
          (__attribute__((address_space(3))) void*)(dst + j*512), 16, 0, 0);
    }
  };

  while (true){
    __syncthreads();                         // full drain (chunk boundary)
    if (tid == 0) item_s = atomicAdd(&ctrl[4 + n], 1);
    __syncthreads();
    int chunk = item_s;
    if (chunk >= nchunks) break;

    if (tid < MR){
      int idx = chunk*MR + tid;
      epl[tid] = (idx < E) ? sorted[idx] : 0u;
    }
    for (int i = tid; i < MR*Hh/4; i += 256){
      ((ushort4*)h0l)[i] = make_ushort4(0,0,0,0);
      ((ushort4*)h1l)[i] = make_ushort4(0,0,0,0);
    }
    __syncthreads();

    unsigned int ep0 = epl[0];
    int maxlen = (ep0 >> 31) ? (int)(ep0 & 255) + 1 : 0;

    float c0r[16][2], c1r[16][2];
    #pragma unroll
    for (int i = 0; i < 16; i++)
      #pragma unroll
      for (int m = 0; m < 2; m++){ c0r[i][m]=0.f; c1r[i][m]=0.f; }

    // prime the weight pipeline: L0 kb=0, units u=0 (half 0) and u=1 (half 1)
    issue_unit(0, 0, 0, 0);
    issue_unit(0, 0, 1, 1);

    #pragma unroll 1
    for (int s = 0; s < maxlen; s++){
      // ---- stage x_t (fp32 -> bf16, swizzled; zeros for finished lanes) ----
      #pragma unroll
      for (int r2 = 0; r2 < 2; r2++){
        int row = r2*16 + (tid >> 4);
        int d4  = (tid & 15) * 4;
        unsigned int pk = epl[row];
        int len = (pk >> 31) ? (int)(pk & 255) + 1 : 0;
        ushort4 u = make_ushort4(0,0,0,0);
        if (s < len){
          int b = (pk >> 16) & 127;
          int t = (int)((pk >> 8) & 255) + s;
          const float* xp = x_in + (((size_t)b*Tt + t)*Nn + n)*Dd + d4;
          f32x4 v = *(const f32x4*)xp;
          u.x = f2bf(v[0]); u.y = f2bf(v[1]); u.z = f2bf(v[2]); u.w = f2bf(v[3]);
        }
        int off = (row*(Dd*2) + d4*2) ^ ((row & 7) << 4);
        *(ushort4*)((char*)xl + off) = u;
      }
      lds_barrier();                                   // bar 1: xl ready

      // ================= LAYER 0 GEMM =================
      {
        f32x4 acc[16][2];
        #pragma unroll
        for (int i = 0; i < 16; i++){
          ushort4 bu = *(const ushort4*)&biasl[(w*16 + i)*16 + nul*4];
          f32x4 bv = { bf2f((short)bu.x), bf2f((short)bu.y),
                       bf2f((short)bu.z), bf2f((short)bu.w) };
          acc[i][0] = bv; acc[i][1] = bv;
        }
        #pragma unroll 1
        for (int kb = 0; kb < 10; kb++){
          bf16x8 a0, a1;
          if (kb < 2){
            a0 = ld_xfrag(xl, 0, kb, l); a1 = ld_xfrag(xl, 1, kb, l);
          } else {
            a0 = ld_hfrag(h0l, 0, kb-2, l); a1 = ld_hfrag(h0l, 1, kb-2, l);
          }
          #pragma unroll
          for (int u = 0; u < 4; u++){
            WAITVM4();
            const unsigned short* rb = wwave + (u & 1)*2048;
            bf16x8 w0 = *(const bf16x8*)(rb + (size_t)l*8);
            bf16x8 w1 = *(const bf16x8*)(rb +  512 + (size_t)l*8);
            bf16x8 w2 = *(const bf16x8*)(rb + 1024 + (size_t)l*8);
            bf16x8 w3 = *(const bf16x8*)(rb + 1536 + (size_t)l*8);
            WAITLGKM0();
            int nxt = kb*4 + u + 2;                 // issue 2 units ahead
            if (nxt < 40) issue_unit(0, nxt >> 2, nxt & 3, u & 1);
            else          issue_unit(1, 0, nxt - 40, u & 1);  // L1 prologue
            int i0 = u*4;
            acc[i0+0][0] = __builtin_amdgcn_mfma_f32_16x16x32_bf16(w0, a0, acc[i0+0][0], 0, 0, 0);
            acc[i0+0][1] = __builtin_amdgcn_mfma_f32_16x16x32_bf16(w0, a1, acc[i0+0][1], 0, 0, 0);
            acc[i0+1][0] = __builtin_amdgcn_mfma_f32_16x16x32_bf16(w1, a0, acc[i0+1][0], 0, 0, 0);
            acc[i0+1][1] = __builtin_amdgcn_mfma_f32_16x16x32_bf16(w1, a1, acc[i0+1][1], 0, 0, 0);
            acc[i0+2][0] = __builtin_amdgcn_mfma_f32_16x16x32_bf16(w2, a0, acc[i0+2][0], 0, 0, 0);
            acc[i0+2][1] = __builtin_amdgcn_mfma_f32_16x16x32_bf16(w2, a1, acc[i0+2][1], 0, 0, 0);
            acc[i0+3][0] = __builtin_amdgcn_mfma_f32_16x16x32_bf16(w3, a0, acc[i0+3][0], 0, 0, 0);
            acc[i0+3][1] = __builtin_amdgcn_mfma_f32_16x16x32_bf16(w3, a1, acc[i0+3][1], 0, 0, 0);
          }
        }
        lds_barrier();   // bar 2: all waves done reading h0l(old)/xl

        // L0 nonlin: gates in acc regs; writes h0l (new)
        #pragma unroll
        for (int i = 0; i < 16; i++){
          #pragma unroll
          for (int m = 0; m < 2; m++){
            f32x4 g = acc[i][m];
            float cn = sigm(g[1])*c0r[i][m] + sigm(g[0])*tanh_s(g[2]);
            float hn = sigm(g[3])*tanh_s(cn);
            c0r[i][m] = cn;
            int row  = m*16 + nrow;
            int unit = (w*16 + i)*4 + nul;
            st_h(h0l, row, unit, f2bf(hn));
            unsigned int pk = epl[row];
            if (pk >> 31){
              int len = (int)(pk & 255) + 1;
              int start = (pk >> 8) & 255;
              if (s == len - 1 && start + len == Tt){
                int b = (pk >> 16) & 127;
                size_t base = ((size_t)(b*Nn + n)*2 + 0)*Hh + unit;
                out[OUT_HN + base] = hn;
                out[OUT_CN + base] = cn;
              }
            }
          }
        }
      }
      lds_barrier();   // bar 3: h0_new visible

      // ================= LAYER 1 GEMM =================
      {
        f32x4 acc[16][2];
        #pragma unroll
        for (int i = 0; i < 16; i++){
          ushort4 bu = *(const ushort4*)&biasl[G4H + (w*16 + i)*16 + nul*4];
          f32x4 bv = { bf2f((short)bu.x), bf2f((short)bu.y),
                       bf2f((short)bu.z), bf2f((short)bu.w) };
          acc[i][0] = bv; acc[i][1] = bv;
        }
        #pragma unroll 1
        for (int kb = 0; kb < 16; kb++){
          bf16x8 a0, a1;
          if (kb < 8){
            a0 = ld_hfrag(h0l, 0, kb, l); a1 = ld_hfrag(h0l, 1, kb, l);
          } else {
            a0 = ld_hfrag(h1l, 0, kb-8, l); a1 = ld_hfrag(h1l, 1, kb-8, l);
          }
          #pragma unroll
          for (int u = 0; u < 4; u++){
            WAITVM4();
            const unsigned short* rb = wwave + (u & 1)*2048;
            bf16x8 w0 = *(const bf16x8*)(rb + (size_t)l*8);
            bf16x8 w1 = *(const bf16x8*)(rb +  512 + (size_t)l*8);
            bf16x8 w2 = *(const bf16x8*)(rb + 1024 + (size_t)l*8);
            bf16x8 w3 = *(const bf16x8*)(rb + 1536 + (size_t)l*8);
            WAITLGKM0();
            int nxt = kb*4 + u + 2;
            if (nxt < 64)            issue_unit(1, nxt >> 2, nxt & 3, u & 1);
            else if (s + 1 < maxlen) issue_unit(0, 0, nxt - 64, u & 1);  // next step L0
            int i0 = u*4;
            acc[i0+0][0] = __builtin_amdgcn_mfma_f32_16x16x32_bf16(w0, a0, acc[i0+0][0], 0, 0, 0);
            acc[i0+0][1] = __builtin_amdgcn_mfma_f32_16x16x32_bf16(w0, a1, acc[i0+0][1], 0, 0, 0);
            acc[i0+1][0] = __builtin_amdgcn_mfma_f32_16x16x32_bf16(w1, a0, acc[i0+1][0], 0, 0, 0);
            acc[i0+1][1] = __builtin_amdgcn_mfma_f32_16x16x32_bf16(w1, a1, acc[i0+1][1], 0, 0, 0);
            acc[i0+2][0] = __builtin_amdgcn_mfma_f32_16x16x32_bf16(w2, a0, acc[i0+2][0], 0, 0, 0);
            acc[i0+2][1] = __builtin_amdgcn_mfma_f32_16x16x32_bf16(w2, a1, acc[i0+2][1], 0, 0, 0);
            acc[i0+3][0] = __builtin_amdgcn_mfma_f32_16x16x32_bf16(w3, a0, acc[i0+3][0], 0, 0, 0);
            acc[i0+3][1] = __builtin_amdgcn_mfma_f32_16x16x32_bf16(w3, a1, acc[i0+3][1], 0, 0, 0);
          }
        }
        lds_barrier();   // bar 4: all waves done reading h0_new/h1l(old)

        // L1 nonlin: writes h1l (new)
        #pragma unroll
        for (int i = 0; i < 16; i++){
          #pragma unroll
          for (int m = 0; m < 2; m++){
            f32x4 g = acc[i][m];
            float cn = sigm(g[1])*c1r[i][m] + sigm(g[0])*tanh_s(g[2]);
            float hn = sigm(g[3])*tanh_s(cn);
            c1r[i][m] = cn;
            int row  = m*16 + nrow;
            int unit = (w*16 + i)*4 + nul;
            st_h(h1l, row, unit, f2bf(hn));
            unsigned int pk = epl[row];
            if (pk >> 31){
              int len = (int)(pk & 255) + 1;
              int start = (pk >> 8) & 255;
              if (s == len - 1 && start + len == Tt){
                int b = (pk >> 16) & 127;
                size_t base = ((size_t)(b*Nn + n)*2 + 1)*Hh + unit;
                out[OUT_HN + base] = hn;
                out[OUT_CN + base] = cn;
              }
            }
          }
        }
      }
      lds_barrier();   // bar 5: h1_new visible for output read

      // ---- output write: output[b, t, n, :] = h1_new (256B segments) ----
      #pragma unroll
      for (int r2 = 0; r2 < 2; r2++){
        int row = r2*16 + (tid >> 4);
        unsigned int pk = epl[row];
        int len = (pk >> 31) ? (int)(pk & 255) + 1 : 0;
        if (s < len){
          int b = (pk >> 16) & 127;
          int t = (int)((pk >> 8) & 255) + s;
          int l16 = tid & 15;
          int swz = (row & 7) << 4;
          float* op = out + (((size_t)b*Tt + t)*Nn + n)*Hh;
          #pragma unroll
          for (int k = 0; k < 4; k++){
            int off = (row*(Hh*2) + k*128 + l16*8) ^ swz;
            ushort4 u = *(const ushort4*)((const char*)h1l + off);
            f32x4 v = { bf2f((short)u.x), bf2f((short)u.y), bf2f((short)u.z), bf2f((short)u.w) };
            *(f32x4*)(op + k*64 + l16*4) = v;
          }
        }
      }
      // no trailing barrier: next h1l writers are >=3 barriers away
    } // s loop
  } // work loop
}

// ============== launch ==============
extern "C" void kernel_launch(void* const* d_in, const int* in_sizes, int n_in,
                              void* d_out, int out_size, void* d_ws, size_t ws_size,
                              hipStream_t stream)
{
  const float* x    = (const float*)d_in[0];
  const unsigned char* ii = (const unsigned char*)d_in[1];
  const float* Wih0 = (const float*)d_in[2];
  const float* Whh0 = (const float*)d_in[3];
  const float* bih0 = (const float*)d_in[4];
  const float* bhh0 = (const float*)d_in[5];
  const float* Wih1 = (const float*)d_in[6];
  const float* Whh1 = (const float*)d_in[7];
  const float* bih1 = (const float*)d_in[8];
  const float* bhh1 = (const float*)d_in[9];
  float* out = (float*)d_out;
  char* ws = (char*)d_ws;

  int* ctrl = (int*)(ws + WS_CTRL);
  unsigned int* sorted = (unsigned int*)(ws + WS_SORT);
  float* bpk = (float*)(ws + WS_BIAS);
  unsigned short* wpkp = (unsigned short*)(ws + WS_WPK);

  hipMemsetAsync(d_ws, 0, 1024, stream);
  k_prep  <<<1, 128, 0, stream>>>(ii, ctrl, sorted);
  k_packw <<<Nn*TILES_PER_AGENT, 64, 0, stream>>>(Wih0, Whh0, Wih1, Whh1,
                                                  bih0, bhh0, bih1, bhh1, wpkp, bpk);
  k_main  <<<512, 256, 0, stream>>>(x, wpkp, bpk, sorted, ctrl, out);
}

// Round 14
// 745.435 us; speedup vs baseline: 1.5484x; 1.1496x over previous
//
#include <hip/hip_runtime.h>
#include <stdint.h>

// Problem constants
#define Bb   128
#define Tt   256
#define Nn   4
#define Dd   64
#define Hh   256
#define G4H  1024          // 4*H
#define MR   32            // episode lanes (rows) per work item

// d_out layout: output (B,T,N,H) | h_n (B,N,L,H) | c_n (B,N,L,H)
#define OUT_HN 33554432    // 128*256*4*256
#define OUT_CN 33816576    // OUT_HN + 128*4*2*256

// workspace byte offsets
#define WS_CTRL 0          // 64 ints: [0]=stride mode, [1]=E, [2]=nchunks, [4..7]=work ctrs
#define WS_SORT 8192       // 32768 u32 packed episodes (sorted desc by len)
#define WS_BIAS 139264     // N*2*1024 f32 packed bias
#define WS_WPK  262144     // packed bf16 weights: 4 agents * 1664 tiles * 1KB
#define TILES_PER_AGENT 1664   // 64 ntiles * (10 kb L0 + 16 kb L1)

typedef __attribute__((ext_vector_type(4))) float f32x4;
typedef __attribute__((ext_vector_type(8))) short bf16x8;

__device__ __forceinline__ unsigned short f2bf(float f){
  union { float f; unsigned u; } v; v.f = f;
  unsigned r = v.u + 0x7FFFu + ((v.u >> 16) & 1u);  // RNE
  return (unsigned short)(r >> 16);
}
__device__ __forceinline__ float bf2f(short s){
  union { unsigned u; float f; } v; v.u = ((unsigned)(unsigned short)s) << 16;
  return v.f;
}
__device__ __forceinline__ float sigm(float x){
  return __builtin_amdgcn_rcpf(1.f + __expf(-x));
}
__device__ __forceinline__ float tanh_s(float x){
  return 1.f - 2.f * __builtin_amdgcn_rcpf(1.f + __expf(2.f * x));
}

// LDS-only barrier: drains DS ops but NOT vmcnt -> in-flight weight loads
// (now plain global_load into VGPRs) survive across barriers.
__device__ __forceinline__ void lds_barrier(){
  asm volatile("s_waitcnt lgkmcnt(0)" ::: "memory");
  __builtin_amdgcn_s_barrier();
  __builtin_amdgcn_sched_barrier(0);
}

// ---- LDS swizzle helpers (XOR bit4 with row&7 -> conflict-free b128 column reads) ----
__device__ __forceinline__ void st_h(unsigned short* hl, int row, int col, unsigned short v){
  int off = (row * (Hh*2) + col * 2) ^ ((row & 7) << 4);
  *(unsigned short*)((char*)hl + off) = v;
}
__device__ __forceinline__ bf16x8 ld_hfrag(const unsigned short* hl, int m, int kb, int l){
  int row = m*16 + (l & 15);
  int off = (row * (Hh*2) + kb*64 + ((l >> 4) << 4)) ^ ((row & 7) << 4);
  return *(const bf16x8*)((const char*)hl + off);
}
__device__ __forceinline__ bf16x8 ld_xfrag(const unsigned short* xl, int m, int kb, int l){
  int row = m*16 + (l & 15);
  int off = (row * (Dd*2) + kb*64 + ((l >> 4) << 4)) ^ ((row & 7) << 4);
  return *(const bf16x8*)((const char*)xl + off);
}

__device__ __forceinline__ bool get_flag(const unsigned char* p, int t, int stride){
  if (stride == 1) return p[t] != 0;
  return ((const int*)p)[t] != 0;
}

// ============== prep kernels (2 dispatches before k_main) ==============

// Fused: detect stride + histogram + scan + scatter (one 128-thread block).
__global__ void k_prep(const unsigned char* ii, int* ctrl, unsigned int* sorted){
  __shared__ int s_cnt;
  __shared__ int hist_s[Tt + 1];
  __shared__ int offs_s[Tt + 1];
  int tid = threadIdx.x;          // 128 threads, one per b
  if (tid == 0) s_cnt = 0;
  for (int i = tid; i <= Tt; i += 128) hist_s[i] = 0;
  __syncthreads();
  atomicAdd(&s_cnt, (ii[2*tid] != 0) + (ii[2*tid+1] != 0));
  __syncthreads();
  int stride = (s_cnt > 80) ? 1 : 4;
  if (tid == 0) ctrl[0] = stride;
  const unsigned char* p = ii + (size_t)tid * Tt * stride;
  int start = 0;
  for (int t = 1; t < Tt; t++){
    if (get_flag(p, t, stride)){ atomicAdd(&hist_s[t - start], 1); start = t; }
  }
  atomicAdd(&hist_s[Tt - start], 1);
  __syncthreads();
  if (tid == 0){
    int run = 0;
    for (int len = Tt; len >= 1; len--){ offs_s[len] = run; run += hist_s[len]; }
    ctrl[1] = run;                     // E
    ctrl[2] = (run + MR - 1) / MR;     // nchunks
  }
  __syncthreads();
  start = 0;
  for (int t = 1; t < Tt; t++){
    if (get_flag(p, t, stride)){
      int len = t - start;
      int pos = atomicAdd(&offs_s[len], 1);
      sorted[pos] = 0x80000000u | ((unsigned)tid << 16) | ((unsigned)start << 8) | (unsigned)(len - 1);
      start = t;
    }
  }
  int len = Tt - start;
  int pos = atomicAdd(&offs_s[len], 1);
  sorted[pos] = 0x80000000u | ((unsigned)tid << 16) | ((unsigned)start << 8) | (unsigned)(len - 1);
}

__global__ void k_packw(const float* __restrict__ Wih0, const float* __restrict__ Whh0,
                        const float* __restrict__ Wih1, const float* __restrict__ Whh1,
                        const float* __restrict__ bih0, const float* __restrict__ bhh0,
                        const float* __restrict__ bih1, const float* __restrict__ bhh1,
                        unsigned short* __restrict__ wpk, float* __restrict__ bpk){
  int bid = blockIdx.x;            // 0..6655
  int l = threadIdx.x;             // 0..63
  int n = bid / TILES_PER_AGENT;
  int r = bid % TILES_PER_AGENT;
  int layer, ntile, kb;
  if (r < 640){ layer = 0; ntile = r / 10; kb = r % 10; }
  else        { layer = 1; r -= 640; ntile = r / 16; kb = r % 16; }
  int col_sub = l >> 2;
  int k8      = (l & 3) * 8;
  int col  = ntile*16 + col_sub;
  int grow = (col & 3)*Hh + (col >> 2);
  const float* src;
  if (layer == 0){
    if (kb < 2) src = Wih0 + ((size_t)(n*G4H + grow))*Dd + kb*32 + k8;
    else        src = Whh0 + ((size_t)(n*G4H + grow))*Hh + (kb-2)*32 + k8;
  } else {
    if (kb < 8) src = Wih1 + ((size_t)(n*G4H + grow))*Hh + kb*32 + k8;
    else        src = Whh1 + ((size_t)(n*G4H + grow))*Hh + (kb-8)*32 + k8;
  }
  int tl = (layer == 0) ? (ntile*10 + kb) : (640 + ntile*16 + kb);
  int lp = ((l & 3) << 4) | (l >> 2);
  unsigned short* dst = wpk + (((size_t)n*TILES_PER_AGENT + tl)*64 + lp)*8;
  #pragma unroll
  for (int j = 0; j < 8; j++) dst[j] = f2bf(src[j]);

  int id = bid*64 + l;
  if (id < Nn*2*G4H){
    int nb = id >> 11; int rb = id & 2047; int lyr = rb >> 10; int c = rb & 1023;
    int gr = (c & 3)*Hh + (c >> 2);
    float v = (lyr == 0) ? (bih0[nb*G4H + gr] + bhh0[nb*G4H + gr])
                         : (bih1[nb*G4H + gr] + bhh1[nb*G4H + gr]);
    bpk[id] = v;
  }
}

// ============== main kernel ==============
// R14: 256 blocks x 256 threads (4 waves), FORCED 1 block/CU via LDS pad.
// 1 wave/SIMD -> 512-VGPR budget (m08/m24/m69): weights stream L2 -> VGPR
// directly (register ping-pong wA/wB, unit = 8 tiles), ZERO LDS traffic for
// weights. R12/R13 post-mortem: gload_lds routed 1.66MB/step through the LDS
// port TWICE (write+read) -> ~14-26us/step of pure LDS time; the critical
// path (longest chunk, ~25 sequential steps on ONE CU) was LDS/port-bound at
// ~31us/step. New floor: per-CU L2 read port 1.66MB / 144GB/s ~= 11.5us/step.
// Registers: acc[16][2](128) + c(64) + wA/wB(64) + misc ~= 300 <= 512.
// Agent = (blockIdx>>1)&3: static (deterministic, no R4 hazard), pairs agent
// to XCDs {2n,2n+1} under round-robin placement (perf-only assumption).
__launch_bounds__(256, 1)
__global__ void k_main(const float* __restrict__ x_in,
                       const unsigned short* __restrict__ wpk,
                       const float* __restrict__ bpk,
                       const unsigned int* __restrict__ sorted,
                       int* __restrict__ ctrl,
                       float* __restrict__ out)
{
  __shared__ unsigned short h0l[MR*Hh];     // 16KB, swizzled bf16
  __shared__ unsigned short h1l[MR*Hh];     // 16KB
  __shared__ unsigned short xl [MR*Dd];     // 4KB
  __shared__ unsigned short biasl[2*G4H];   // 4KB bf16 packed bias
  __shared__ unsigned int epl[MR];
  __shared__ int item_s;
  __shared__ char lds_pad[45056];           // pad -> ~85KB total -> 1 block/CU

  const int tid = threadIdx.x;
  const int w   = tid >> 6;                 // wave 0..3
  const int l   = tid & 63;
  const int n   = (blockIdx.x >> 1) & 3;    // static agent; 64 blocks/agent
  const int E       = ctrl[1];
  const int nchunks = ctrl[2];

  // keep the pad allocated (runtime-opaque condition, never true)
  if (E == -2147483647) lds_pad[tid] = 1;

  const unsigned short* wbase = wpk + (size_t)n * TILES_PER_AGENT * 64 * 8;

  for (int i = tid; i < 2*G4H; i += 256) biasl[i] = f2bf(bpk[n*2*G4H + i]);

  const int nrow = l & 15;
  const int nul  = l >> 4;

  // Weight unit: 8 tiles (i = h*8 + j, j<8) of (layer,kb) for this wave,
  // loaded straight into VGPRs. Tile id: L0 = t*10+kb, L1 = 640+t*16+kb.
  #define LOADW(dstv, layer, kb, h)                                          \
    { int base_ = ((layer)==0) ? ((w*16 + (h)*8)*10 + (kb))                  \
                               : (640 + (w*16 + (h)*8)*16 + (kb));           \
      int str_  = ((layer)==0) ? 10 : 16;                                    \
      _Pragma("unroll")                                                      \
      for (int j = 0; j < 8; j++)                                            \
        dstv[j] = *(const bf16x8*)(wbase + ((size_t)(base_ + j*str_)*64 + l)*8); \
      __builtin_amdgcn_sched_barrier(0); }

  #define MFMA8(wv, h)                                                       \
    { _Pragma("unroll")                                                      \
      for (int j = 0; j < 8; j++){                                           \
        int i_ = (h)*8 + j;                                                  \
        acc[i_][0] = __builtin_amdgcn_mfma_f32_16x16x32_bf16(wv[j], a0, acc[i_][0], 0, 0, 0); \
        acc[i_][1] = __builtin_amdgcn_mfma_f32_16x16x32_bf16(wv[j], a1, acc[i_][1], 0, 0, 0); \
      } }

  while (true){
    __syncthreads();                         // full drain (chunk boundary)
    if (tid == 0) item_s = atomicAdd(&ctrl[4 + n], 1);
    __syncthreads();
    int chunk = item_s;
    if (chunk >= nchunks) break;

    if (tid < MR){
      int idx = chunk*MR + tid;
      epl[tid] = (idx < E) ? sorted[idx] : 0u;
    }
    for (int i = tid; i < MR*Hh/4; i += 256){
      ((ushort4*)h0l)[i] = make_ushort4(0,0,0,0);
      ((ushort4*)h1l)[i] = make_ushort4(0,0,0,0);
    }
    __syncthreads();

    unsigned int ep0 = epl[0];
    int maxlen = (ep0 >> 31) ? (int)(ep0 & 255) + 1 : 0;

    float c0r[16][2], c1r[16][2];
    #pragma unroll
    for (int i = 0; i < 16; i++)
      #pragma unroll
      for (int m = 0; m < 2; m++){ c0r[i][m]=0.f; c1r[i][m]=0.f; }

    bf16x8 wA[8], wB[8];
    LOADW(wA, 0, 0, 0);          // prime: L0 kb=0, halves 0/1
    LOADW(wB, 0, 0, 1);

    #pragma unroll 1
    for (int s = 0; s < maxlen; s++){
      // ---- stage x_t (fp32 -> bf16, swizzled; zeros for finished lanes) ----
      #pragma unroll
      for (int r2 = 0; r2 < 2; r2++){
        int row = r2*16 + (tid >> 4);
        int d4  = (tid & 15) * 4;
        unsigned int pk = epl[row];
        int len = (pk >> 31) ? (int)(pk & 255) + 1 : 0;
        ushort4 u = make_ushort4(0,0,0,0);
        if (s < len){
          int b = (pk >> 16) & 127;
          int t = (int)((pk >> 8) & 255) + s;
          const float* xp = x_in + (((size_t)b*Tt + t)*Nn + n)*Dd + d4;
          f32x4 v = *(const f32x4*)xp;
          u.x = f2bf(v[0]); u.y = f2bf(v[1]); u.z = f2bf(v[2]); u.w = f2bf(v[3]);
        }
        int off = (row*(Dd*2) + d4*2) ^ ((row & 7) << 4);
        *(ushort4*)((char*)xl + off) = u;
      }
      lds_barrier();                                   // bar 1: xl ready

      // ================= LAYER 0 GEMM =================
      {
        f32x4 acc[16][2];
        #pragma unroll
        for (int i = 0; i < 16; i++){
          ushort4 bu = *(const ushort4*)&biasl[(w*16 + i)*16 + nul*4];
          f32x4 bv = { bf2f((short)bu.x), bf2f((short)bu.y),
                       bf2f((short)bu.z), bf2f((short)bu.w) };
          acc[i][0] = bv; acc[i][1] = bv;
        }
        #pragma unroll 1
        for (int kb = 0; kb < 10; kb++){
          bf16x8 a0, a1;
          if (kb < 2){ a0 = ld_xfrag(xl, 0, kb, l);    a1 = ld_xfrag(xl, 1, kb, l); }
          else       { a0 = ld_hfrag(h0l, 0, kb-2, l); a1 = ld_hfrag(h0l, 1, kb-2, l); }
          MFMA8(wA, 0);
          if (kb < 9) { LOADW(wA, 0, kb+1, 0); } else { LOADW(wA, 1, 0, 0); }
          MFMA8(wB, 1);
          if (kb < 9) { LOADW(wB, 0, kb+1, 1); } else { LOADW(wB, 1, 0, 1); }
        }
        lds_barrier();   // bar 2: all waves done reading h0l(old)/xl

        // L0 nonlin: gates in acc regs; writes h0l (new). wA/wB loads (L1
        // unit 0) fly underneath this VALU section.
        #pragma unroll
        for (int i = 0; i < 16; i++){
          #pragma unroll
          for (int m = 0; m < 2; m++){
            f32x4 g = acc[i][m];
            float cn = sigm(g[1])*c0r[i][m] + sigm(g[0])*tanh_s(g[2]);
            float hn = sigm(g[3])*tanh_s(cn);
            c0r[i][m] = cn;
            int row  = m*16 + nrow;
            int unit = (w*16 + i)*4 + nul;
            st_h(h0l, row, unit, f2bf(hn));
            unsigned int pk = epl[row];
            if (pk >> 31){
              int len = (int)(pk & 255) + 1;
              int start = (pk >> 8) & 255;
              if (s == len - 1 && start + len == Tt){
                int b = (pk >> 16) & 127;
                size_t base = ((size_t)(b*Nn + n)*2 + 0)*Hh + unit;
                out[OUT_HN + base] = hn;
                out[OUT_CN + base] = cn;
              }
            }
          }
        }
      }
      lds_barrier();   // bar 3: h0_new visible

      // ================= LAYER 1 GEMM =================
      {
        f32x4 acc[16][2];
        #pragma unroll
        for (int i = 0; i < 16; i++){
          ushort4 bu = *(const ushort4*)&biasl[G4H + (w*16 + i)*16 + nul*4];
          f32x4 bv = { bf2f((short)bu.x), bf2f((short)bu.y),
                       bf2f((short)bu.z), bf2f((short)bu.w) };
          acc[i][0] = bv; acc[i][1] = bv;
        }
        #pragma unroll 1
        for (int kb = 0; kb < 16; kb++){
          bf16x8 a0, a1;
          if (kb < 8){ a0 = ld_hfrag(h0l, 0, kb, l);   a1 = ld_hfrag(h0l, 1, kb, l); }
          else       { a0 = ld_hfrag(h1l, 0, kb-8, l); a1 = ld_hfrag(h1l, 1, kb-8, l); }
          MFMA8(wA, 0);
          if (kb < 15) { LOADW(wA, 1, kb+1, 0); } else { LOADW(wA, 0, 0, 0); }
          MFMA8(wB, 1);
          if (kb < 15) { LOADW(wB, 1, kb+1, 1); } else { LOADW(wB, 0, 0, 1); }
        }
        lds_barrier();   // bar 4: all waves done reading h0_new/h1l(old)

        // L1 nonlin: writes h1l (new). Next step's L0 unit-0 loads in flight.
        #pragma unroll
        for (int i = 0; i < 16; i++){
          #pragma unroll
          for (int m = 0; m < 2; m++){
            f32x4 g = acc[i][m];
            float cn = sigm(g[1])*c1r[i][m] + sigm(g[0])*tanh_s(g[2]);
            float hn = sigm(g[3])*tanh_s(cn);
            c1r[i][m] = cn;
            int row  = m*16 + nrow;
            int unit = (w*16 + i)*4 + nul;
            st_h(h1l, row, unit, f2bf(hn));
            unsigned int pk = epl[row];
            if (pk >> 31){
              int len = (int)(pk & 255) + 1;
              int start = (pk >> 8) & 255;
              if (s == len - 1 && start + len == Tt){
                int b = (pk >> 16) & 127;
                size_t base = ((size_t)(b*Nn + n)*2 + 1)*Hh + unit;
                out[OUT_HN + base] = hn;
                out[OUT_CN + base] = cn;
              }
            }
          }
        }
      }
      lds_barrier();   // bar 5: h1_new visible for output read

      // ---- output write: output[b, t, n, :] = h1_new (256B segments) ----
      #pragma unroll
      for (int r2 = 0; r2 < 2; r2++){
        int row = r2*16 + (tid >> 4);
        unsigned int pk = epl[row];
        int len = (pk >> 31) ? (int)(pk & 255) + 1 : 0;
        if (s < len){
          int b = (pk >> 16) & 127;
          int t = (int)((pk >> 8) & 255) + s;
          int l16 = tid & 15;
          int swz = (row & 7) << 4;
          float* op = out + (((size_t)b*Tt + t)*Nn + n)*Hh;
          #pragma unroll
          for (int k = 0; k < 4; k++){
            int off = (row*(Hh*2) + k*128 + l16*8) ^ swz;
            ushort4 u = *(const ushort4*)((const char*)h1l + off);
            f32x4 v = { bf2f((short)u.x), bf2f((short)u.y), bf2f((short)u.z), bf2f((short)u.w) };
            *(f32x4*)(op + k*64 + l16*4) = v;
          }
        }
      }
      // no trailing barrier: next h1l writers are >=3 barriers away
    } // s loop
  } // work loop
  #undef LOADW
  #undef MFMA8
}

// ============== launch ==============
extern "C" void kernel_launch(void* const* d_in, const int* in_sizes, int n_in,
                              void* d_out, int out_size, void* d_ws, size_t ws_size,
                              hipStream_t stream)
{
  const float* x    = (const float*)d_in[0];
  const unsigned char* ii = (const unsigned char*)d_in[1];
  const float* Wih0 = (const float*)d_in[2];
  const float* Whh0 = (const float*)d_in[3];
  const float* bih0 = (const float*)d_in[4];
  const float* bhh0 = (const float*)d_in[5];
  const float* Wih1 = (const float*)d_in[6];
  const float* Whh1 = (const float*)d_in[7];
  const float* bih1 = (const float*)d_in[8];
  const float* bhh1 = (const float*)d_in[9];
  float* out = (float*)d_out;
  char* ws = (char*)d_ws;

  int* ctrl = (int*)(ws + WS_CTRL);
  unsigned int* sorted = (unsigned int*)(ws + WS_SORT);
  float* bpk = (float*)(ws + WS_BIAS);
  unsigned short* wpkp = (unsigned short*)(ws + WS_WPK);

  hipMemsetAsync(d_ws, 0, 1024, stream);
  k_prep  <<<1, 128, 0, stream>>>(ii, ctrl, sorted);
  k_packw <<<Nn*TILES_PER_AGENT, 64, 0, stream>>>(Wih0, Whh0, Wih1, Whh1,
                                                  bih0, bhh0, bih1, bhh1, wpkp, bpk);
  k_main  <<<256, 256, 0, stream>>>(x, wpkp, bpk, sorted, ctrl, out);
}